// Round 7
// baseline (738.119 us; speedup 1.0000x reference)
//
#include <hip/hip_runtime.h>
#include <hip/hip_bf16.h>

#define N_NODES 100000
#define N_EDGES 1600000
#define N_GRAPHS 1024
#define F_NODE 16
#define F_EDGE 8
#define F_GRAPH 10
#define HD 64
#define HD2 128
#define GEN_EPS 1e-7f
#define SCAN_NBLK ((N_NODES + 255) / 256)   // 391

typedef unsigned short u16;
typedef unsigned int u32;
typedef __attribute__((ext_vector_type(8))) short short8;
typedef __attribute__((ext_vector_type(4))) float floatx4;

__device__ __forceinline__ u16 f2bf(float x) {   // RNE bf16 (finite inputs)
    u32 u = __float_as_uint(x);
    return (u16)((u + 0x7FFFu + ((u >> 16) & 1u)) >> 16);
}
__device__ __forceinline__ float bf2f(u16 u) {
    return __uint_as_float(((u32)u) << 16);
}
__device__ __forceinline__ float u2f(unsigned int u) {
    return __uint_as_float(u);
}

// h[n][f] = node_b[f] + sum_k x[n][k]*node_W[k][f]; also emits bf16 mirror hb.
__global__ void __launch_bounds__(256) k_node_embed(
        const float* __restrict__ x, const float* __restrict__ W,
        const float* __restrict__ b, float* __restrict__ h,
        u16* __restrict__ hb) {
    __shared__ float sW[F_NODE * HD];
    __shared__ float sb[HD];
    for (int i = threadIdx.x; i < F_NODE * HD; i += 256) sW[i] = W[i];
    if (threadIdx.x < HD) sb[threadIdx.x] = b[threadIdx.x];
    __syncthreads();
    int t = blockIdx.x * 256 + threadIdx.x;
    if (t >= N_NODES * HD) return;
    int n = t >> 6, f = t & 63;
    const float* xr = x + (size_t)n * F_NODE;
    float acc = sb[f];
#pragma unroll
    for (int k = 0; k < F_NODE; k++) acc += xr[k] * sW[k * HD + f];
    h[t] = acc;
    hb[t] = f2bf(acc);
}

// ---- CSR build ----
__global__ void __launch_bounds__(256) k_hist(
        const int* __restrict__ dst, int* __restrict__ deg,
        int* __restrict__ rank) {
    int e = blockIdx.x * 256 + threadIdx.x;
    if (e >= N_EDGES) return;
    rank[e] = atomicAdd(&deg[dst[e]], 1);
}

__global__ void __launch_bounds__(256) k_scan1(
        const int* __restrict__ deg, int* __restrict__ bsum) {
    __shared__ int red[256];
    int t = threadIdx.x;
    int g = blockIdx.x * 256 + t;
    red[t] = (g < N_NODES) ? deg[g] : 0;
    __syncthreads();
    for (int s = 128; s > 0; s >>= 1) {
        if (t < s) red[t] += red[t + s];
        __syncthreads();
    }
    if (t == 0) bsum[blockIdx.x] = red[0];
}

__global__ void __launch_bounds__(512) k_scan2(
        const int* __restrict__ bsum, int* __restrict__ bpre) {
    __shared__ int sh[512];
    int t = threadIdx.x;
    int v = (t < SCAN_NBLK) ? bsum[t] : 0;
    sh[t] = v;
    __syncthreads();
    for (int d = 1; d < 512; d <<= 1) {
        int u = (t >= d) ? sh[t - d] : 0;
        __syncthreads();
        sh[t] += u;
        __syncthreads();
    }
    if (t < SCAN_NBLK) bpre[t] = sh[t] - v;   // exclusive
}

__global__ void __launch_bounds__(256) k_scan3(
        const int* __restrict__ deg, const int* __restrict__ bpre,
        int* __restrict__ off) {
    __shared__ int sh[256];
    int t = threadIdx.x;
    int g = blockIdx.x * 256 + t;
    int v = (g < N_NODES) ? deg[g] : 0;
    sh[t] = v;
    __syncthreads();
    for (int d = 1; d < 256; d <<= 1) {
        int u = (t >= d) ? sh[t - d] : 0;
        __syncthreads();
        sh[t] += u;
        __syncthreads();
    }
    int incl = sh[t];
    int base = bpre[blockIdx.x];
    if (g < N_NODES) off[g] = base + incl - v;
    if (g == N_NODES - 1) off[N_NODES] = base + incl;
}

// Scatter edge attrs (verbatim) + separate srcs[] array.
__global__ void __launch_bounds__(256) k_scatter(
        const int* __restrict__ src, const int* __restrict__ dst,
        const int* __restrict__ rank, const int* __restrict__ off,
        const float* __restrict__ eattr,
        unsigned int* __restrict__ rec, int* __restrict__ srcs) {
    int e = blockIdx.x * 256 + threadIdx.x;
    if (e >= N_EDGES) return;
    const uint4* ap = reinterpret_cast<const uint4*>(eattr + (size_t)e * F_EDGE);
    uint4 a0 = ap[0], a1 = ap[1];           // coalesced 32B read
    int pos = off[dst[e]] + rank[e];
    uint4* op = reinterpret_cast<uint4*>(rec + (size_t)pos * 8);
    op[0] = a0;                              // one 32B sector
    op[1] = a1;
    srcs[pos] = src[e];
}

// Pre-transpose GENConv MLP weights to bf16 once per launch:
// W1t[l][j*64+k] = bf16(W1[l][k*128+j])   (j<128, k<64)
// W2t[l][c*128+j] = bf16(W2[l][j*64+c])   (c<64, j<128)
__global__ void __launch_bounds__(256) k_prep(
        const float* __restrict__ W1a, const float* __restrict__ W2a,
        const float* __restrict__ W1b, const float* __restrict__ W2b,
        const float* __restrict__ W1c, const float* __restrict__ W2c,
        u16* __restrict__ W1t, u16* __restrict__ W2t) {
    int bid = blockIdx.x;           // 192 blocks: 64 per layer
    int l = bid >> 6;
    int t = (bid & 63) * 256 + threadIdx.x;   // [0, 16384)
    const float* W1 = (l == 0) ? W1a : (l == 1) ? W1b : W1c;
    const float* W2 = (l == 0) ? W2a : (l == 1) ? W2b : W2c;
    if (t < HD * HD2) {             // W1t entry
        int j = t >> 6, k = t & 63;
        W1t[(size_t)l * HD * HD2 + t] = f2bf(W1[k * HD2 + j]);
    } else {
        int u = t - HD * HD2;
        int c = u >> 7, j = u & 127;
        W2t[(size_t)l * HD * HD2 + u] = f2bf(W2[j * HD + c]);
    }
}

// ---- Fused GENConv layer: aggregation + MLP, wave-local pipeline ----
// Block = 4 waves = 64 consecutive nodes; wave w owns nodes [nt0, nt0+16).
// Phase 1 (per wave): round-5's proven agg loop (rec via per-lane VMEM +
//   LDS broadcast, srcs via s_load, batched hb gathers, 1-chunk pipeline);
//   result (h + agg) written to the wave's PRIVATE LDS segment.
// Phase 2 (per wave): MFMA MLP on its own 16-node tile. A-frags from the
//   private segment; B-frags from pre-transposed bf16 weights in global
//   (16KB each -> L1-resident); hid staged in the SAME private segment
//   (union; safe: a-frag reads precede hid writes in same-wave program
//   order, and no other wave touches this segment). NO __syncthreads.
// LDS 19.7KB, __launch_bounds__(256,8) pins VGPR<=64 -> 8 blocks/CU
// (round-4 lesson: occupancy is the life-or-death parameter here).
__global__ void __launch_bounds__(256, 8) k_layer(
        const float* __restrict__ hin, const u16* __restrict__ hbin,
        const int* __restrict__ off,
        const unsigned int* __restrict__ rec,
        const int* __restrict__ srcs,
        const float* __restrict__ eW, const float* __restrict__ eb,
        const u16* __restrict__ W1t, const float* __restrict__ b1,
        const u16* __restrict__ W2t, const float* __restrict__ b2,
        float* __restrict__ hout, u16* __restrict__ hbout) {
    // per-wave segment: sAgg [16][73] f32 (4672B) unioned with sHid [16][136] u16 (4352B)
    __shared__ float segf[4][16 * 73 + 4];
    __shared__ float sAttr[4][64];
    int wid = threadIdx.x >> 6;
    int lane = threadIdx.x & 63;
    float* sAggW = segf[wid];
    u16* sHidW = (u16*)segf[wid];
    int nt0 = blockIdx.x * 64 + wid * 16;
    if (nt0 >= N_NODES) return;     // 100000 % 16 == 0: whole-tile guard

    // ================= phase 1: aggregation of 16 nodes =================
    {
        int f = lane;
        float w[F_EDGE];
#pragma unroll
        for (int k = 0; k < F_EDGE; k++) w[k] = eW[k * HD + f];
        float bfv = eb[f];
        for (int j = 0; j < 16; j++) {
            int n = nt0 + j;                      // wave-uniform
            int beg = off[n], end = off[n + 1];
            float hroot = hin[(size_t)n * HD + f];
            float den = 0.f, nm = 0.f;
            if (beg < end) {
                int i = beg;
                float av = 0.f;
                if (beg + (lane >> 3) < end) av = u2f(rec[(size_t)beg * 8 + lane]);
                int s8[8];
#pragma unroll
                for (int u = 0; u < 8; u++) s8[u] = srcs[beg + u];
                while (true) {
                    float hv[8];
#pragma unroll
                    for (int u = 0; u < 8; u++)
                        hv[u] = bf2f(hbin[(size_t)s8[u] * HD + f]);
                    int inx = i + 8;
                    bool more = inx < end;
                    float avN = 0.f;
                    int s8N[8];
                    if (more) {
                        if (inx + (lane >> 3) < end)
                            avN = u2f(rec[(size_t)inx * 8 + lane]);
#pragma unroll
                        for (int u = 0; u < 8; u++) s8N[u] = srcs[inx + u];
                    } else {
#pragma unroll
                        for (int u = 0; u < 8; u++) s8N[u] = 0;
                    }
                    sAttr[wid][lane] = av;        // same-wave stage, no barrier
#pragma unroll
                    for (int u = 0; u < 8; u++) {
                        if (i + u < end) {        // uniform guard
                            const floatx4* A = reinterpret_cast<const floatx4*>(
                                &sAttr[wid][u * 8]);
                            floatx4 a0 = A[0], a1 = A[1];
                            float ea = bfv + a0.x * w[0] + a0.y * w[1]
                                           + a0.z * w[2] + a0.w * w[3]
                                           + a1.x * w[4] + a1.y * w[5]
                                           + a1.z * w[6] + a1.w * w[7];
                            float r = fmaxf(hv[u] + ea, 0.f);
                            float ev = __expf(r);
                            den += ev;
                            nm += r * ev;
                        }
                    }
                    if (!more) break;
                    i = inx;
                    av = avN;
#pragma unroll
                    for (int u = 0; u < 8; u++) s8[u] = s8N[u];
                }
            }
            float agg = (end > beg) ? (nm / fmaxf(den, 1e-16f) + GEN_EPS) : 0.f;
            sAggW[j * 73 + f] = hroot + agg;
        }
    }

    // ================= phase 2: MLP on this wave's 16-node tile =========
    {
        int quad = lane >> 4, lm = lane & 15;
        // A-frags: row lm of the private sAgg (written by this wave above)
        short8 a[2];
#pragma unroll
        for (int kk = 0; kk < 2; kk++) {
            const floatx4* p = reinterpret_cast<const floatx4*>(
                &sAggW[lm * 73 + kk * 32 + quad * 8]);
            floatx4 v0 = p[0], v1 = p[1];
            short8 t;
            t[0] = (short)f2bf(v0.x); t[1] = (short)f2bf(v0.y);
            t[2] = (short)f2bf(v0.z); t[3] = (short)f2bf(v0.w);
            t[4] = (short)f2bf(v1.x); t[5] = (short)f2bf(v1.y);
            t[6] = (short)f2bf(v1.z); t[7] = (short)f2bf(v1.w);
            a[kk] = t;
        }
        // hid = relu(A @ W1 + b1): B-frags direct from global (L1-resident)
#pragma unroll
        for (int jt = 0; jt < 8; jt++) {
            int jb = jt * 16;
            float bias = b1[jb + lm];
            floatx4 acc = {bias, bias, bias, bias};
#pragma unroll
            for (int kk = 0; kk < 2; kk++) {
                const short8* bp = reinterpret_cast<const short8*>(
                    W1t + (size_t)(jb + lm) * HD + kk * 32 + quad * 8);
                acc = __builtin_amdgcn_mfma_f32_16x16x32_bf16(a[kk], *bp, acc, 0, 0, 0);
            }
#pragma unroll
            for (int r = 0; r < 4; r++)
                sHidW[(quad * 4 + r) * 136 + jb + lm] = f2bf(fmaxf(acc[r], 0.f));
        }
        // out = relu(hid @ W2 + b2)
        short8 a2[4];
#pragma unroll
        for (int kk = 0; kk < 4; kk++)
            a2[kk] = *reinterpret_cast<const short8*>(
                &sHidW[lm * 136 + kk * 32 + quad * 8]);
#pragma unroll
        for (int ct = 0; ct < 4; ct++) {
            int cb = ct * 16;
            float bias = b2[cb + lm];
            floatx4 acc = {bias, bias, bias, bias};
#pragma unroll
            for (int kk = 0; kk < 4; kk++) {
                const short8* bp = reinterpret_cast<const short8*>(
                    W2t + (size_t)(cb + lm) * HD2 + kk * 32 + quad * 8);
                acc = __builtin_amdgcn_mfma_f32_16x16x32_bf16(a2[kk], *bp, acc, 0, 0, 0);
            }
#pragma unroll
            for (int r = 0; r < 4; r++) {
                int orow = nt0 + quad * 4 + r;
                float o = fmaxf(acc[r], 0.f);
                hout[(size_t)orow * HD + cb + lm] = o;
                hbout[(size_t)orow * HD + cb + lm] = f2bf(o);
            }
        }
    }
}

// One wave per graph; range via inline binary search on sorted batch.
__global__ void __launch_bounds__(256) k_pool(
        const float* __restrict__ h, const int* __restrict__ batch,
        float* __restrict__ pooled) {
    int g = blockIdx.x * 4 + (threadIdx.x >> 6);
    if (g >= N_GRAPHS) return;
    int f = threadIdx.x & 63;
    int lo = 0, hi = N_NODES;
    while (lo < hi) {
        int mid = (lo + hi) >> 1;
        if (batch[mid] < g) lo = mid + 1; else hi = mid;
    }
    int b = lo;
    int lo2 = b, hi2 = N_NODES;
    while (lo2 < hi2) {
        int mid = (lo2 + hi2) >> 1;
        if (batch[mid] < g + 1) lo2 = mid + 1; else hi2 = mid;
    }
    int e = lo2;
    float s = 0.f;
    for (int n = b; n < e; n++) s += h[(size_t)n * HD + f];
    float cnt = fmaxf((float)(e - b), 1.f);
    pooled[(size_t)g * HD + f] = s / cnt;
}

__global__ void __launch_bounds__(64) k_head(
        const float* __restrict__ pooled, const float* __restrict__ gattr,
        const float* __restrict__ d1W, const float* __restrict__ d1b,
        const float* __restrict__ d2W, const float* __restrict__ d2b,
        const float* __restrict__ oW, const float* __restrict__ ob,
        float* __restrict__ out) {
    int g = blockIdx.x;
    __shared__ float si[HD + F_GRAPH];
    __shared__ float s1[32], s2[32];
    int t = threadIdx.x;
    if (t < HD) si[t] = pooled[(size_t)g * HD + t];
    if (t < F_GRAPH) si[HD + t] = gattr[(size_t)g * F_GRAPH + t];
    __syncthreads();
    if (t < 32) {
        float acc = d1b[t];
        for (int i = 0; i < HD + F_GRAPH; i++) acc += si[i] * d1W[i * 32 + t];
        s1[t] = fmaxf(acc, 0.f);
    }
    __syncthreads();
    if (t < 32) {
        float acc = d2b[t];
        for (int i = 0; i < 32; i++) acc += s1[i] * d2W[i * 32 + t];
        s2[t] = fmaxf(acc, 0.f);
    }
    __syncthreads();
    if (t == 0) {
        float acc = ob[0];
        for (int i = 0; i < 32; i++) acc += s2[i] * oW[i];
        out[g] = 1.f / (1.f + __expf(-acc));
    }
}

extern "C" void kernel_launch(void* const* d_in, const int* in_sizes, int n_in,
                              void* d_out, int out_size, void* d_ws, size_t ws_size,
                              hipStream_t stream) {
    const float* x     = (const float*)d_in[0];
    const float* eattr = (const float*)d_in[1];
    const float* gattr = (const float*)d_in[2];
    const int*   eidx  = (const int*)d_in[3];
    const int*   batch = (const int*)d_in[4];
    const float* nodeW = (const float*)d_in[5];
    const float* nodeb = (const float*)d_in[6];
    const float* edgeW = (const float*)d_in[7];
    const float* edgeb = (const float*)d_in[8];
    const float* cW1[3] = {(const float*)d_in[9],  (const float*)d_in[13], (const float*)d_in[17]};
    const float* cb1[3] = {(const float*)d_in[10], (const float*)d_in[14], (const float*)d_in[18]};
    const float* cW2[3] = {(const float*)d_in[11], (const float*)d_in[15], (const float*)d_in[19]};
    const float* cb2[3] = {(const float*)d_in[12], (const float*)d_in[16], (const float*)d_in[20]};
    const float* d1W = (const float*)d_in[21];
    const float* d1b = (const float*)d_in[22];
    const float* d2W = (const float*)d_in[23];
    const float* d2b = (const float*)d_in[24];
    const float* oW  = (const float*)d_in[25];
    const float* ob  = (const float*)d_in[26];

    const int* src = eidx;
    const int* dst = eidx + N_EDGES;

    // workspace layout (h/h2 + hb/hb2 double-buffered for the fused layer;
    // srcs +64 zeroed pad, rec +8 records pad for chunked loads)
    char* p = (char*)d_ws;
    float* h      = (float*)p; p += (size_t)N_NODES * HD * 4;       // 25.6 MB
    float* h2     = (float*)p; p += (size_t)N_NODES * HD * 4;       // 25.6 MB
    int*   srcs   = (int*)p;   p += (size_t)(N_EDGES + 64) * 4;     // 6.4 MB + pad
    unsigned int* rec = (unsigned int*)p; p += (size_t)(N_EDGES + 8) * F_EDGE * 4; // 51.2 MB + pad
    u16*   hb     = (u16*)p;   p += (size_t)N_NODES * HD * 2;       // 12.8 MB
    u16*   hb2    = (u16*)p;   p += (size_t)N_NODES * HD * 2;       // 12.8 MB
    u16*   W1t    = (u16*)p;   p += (size_t)3 * HD * HD2 * 2;       // 48 KB
    u16*   W2t    = (u16*)p;   p += (size_t)3 * HD * HD2 * 2;       // 48 KB
    float* pooled = (float*)p; p += (size_t)N_GRAPHS * HD * 4;
    int*   off    = (int*)p;   p += (size_t)(N_NODES + 1) * 4;
    int*   deg    = (int*)p;   p += (size_t)N_NODES * 4;
    int*   rank   = (int*)p;   p += (size_t)N_EDGES * 4;            // 6.4 MB
    int*   bsum   = (int*)p;   p += (size_t)(SCAN_NBLK + 1) * 4;
    int*   bpre   = (int*)p;   p += (size_t)(SCAN_NBLK + 1) * 4;

    const int EB = (N_EDGES + 255) / 256;
    const int NBL = (N_NODES + 63) / 64;   // 1563 fused-layer blocks

    k_node_embed<<<(N_NODES * HD + 255) / 256, 256, 0, stream>>>(x, nodeW, nodeb, h, hb);
    k_prep<<<192, 256, 0, stream>>>(cW1[0], cW2[0], cW1[1], cW2[1], cW1[2], cW2[2],
                                    W1t, W2t);

    // CSR build (atomic-free scatter via hist-captured ranks)
    hipMemsetAsync(deg, 0, (size_t)N_NODES * 4, stream);
    hipMemsetAsync(srcs + N_EDGES, 0, 64 * sizeof(int), stream);   // valid pad
    k_hist<<<EB, 256, 0, stream>>>(dst, deg, rank);
    k_scan1<<<SCAN_NBLK, 256, 0, stream>>>(deg, bsum);
    k_scan2<<<1, 512, 0, stream>>>(bsum, bpre);
    k_scan3<<<SCAN_NBLK, 256, 0, stream>>>(deg, bpre, off);
    k_scatter<<<EB, 256, 0, stream>>>(src, dst, rank, off, eattr, rec, srcs);

    float* ha = h;  u16* hba = hb;
    float* hc = h2; u16* hbc = hb2;
    for (int l = 0; l < 3; l++) {
        k_layer<<<NBL, 256, 0, stream>>>(
            ha, hba, off, rec, srcs, edgeW, edgeb,
            W1t + (size_t)l * HD * HD2, cb1[l],
            W2t + (size_t)l * HD * HD2, cb2[l],
            hc, hbc);
        float* tf = ha; ha = hc; hc = tf;
        u16* tu = hba; hba = hbc; hbc = tu;
    }
    // after 3 swaps the final result is in ha

    k_pool<<<(N_GRAPHS + 3) / 4, 256, 0, stream>>>(ha, batch, pooled);
    k_head<<<N_GRAPHS, 64, 0, stream>>>(pooled, gattr,
                                        d1W, d1b, d2W, d2b, oW, ob,
                                        (float*)d_out);
}

// Round 8
// 712.552 us; speedup vs baseline: 1.0359x; 1.0359x over previous
//
#include <hip/hip_runtime.h>
#include <hip/hip_bf16.h>

#define N_NODES 100000
#define N_EDGES 1600000
#define N_GRAPHS 1024
#define F_NODE 16
#define F_EDGE 8
#define F_GRAPH 10
#define HD 64
#define HD2 128
#define GEN_EPS 1e-7f
#define SCAN_NBLK ((N_NODES + 255) / 256)   // 391

typedef unsigned short u16;
typedef unsigned int u32;
typedef __attribute__((ext_vector_type(8))) short short8;
typedef __attribute__((ext_vector_type(4))) float floatx4;

__device__ __forceinline__ u16 f2bf(float x) {   // RNE bf16 (finite inputs)
    u32 u = __float_as_uint(x);
    return (u16)((u + 0x7FFFu + ((u >> 16) & 1u)) >> 16);
}
__device__ __forceinline__ float bf2f(u16 u) {
    return __uint_as_float(((u32)u) << 16);
}
__device__ __forceinline__ float u2f(unsigned int u) {
    return __uint_as_float(u);
}

// h[n][f] = node_b[f] + sum_k x[n][k]*node_W[k][f]; also emits bf16 mirror hb.
__global__ void __launch_bounds__(256) k_node_embed(
        const float* __restrict__ x, const float* __restrict__ W,
        const float* __restrict__ b, float* __restrict__ h,
        u16* __restrict__ hb) {
    __shared__ float sW[F_NODE * HD];
    __shared__ float sb[HD];
    for (int i = threadIdx.x; i < F_NODE * HD; i += 256) sW[i] = W[i];
    if (threadIdx.x < HD) sb[threadIdx.x] = b[threadIdx.x];
    __syncthreads();
    int t = blockIdx.x * 256 + threadIdx.x;
    if (t >= N_NODES * HD) return;
    int n = t >> 6, f = t & 63;
    const float* xr = x + (size_t)n * F_NODE;
    float acc = sb[f];
#pragma unroll
    for (int k = 0; k < F_NODE; k++) acc += xr[k] * sW[k * HD + f];
    h[t] = acc;
    hb[t] = f2bf(acc);
}

// ---- CSR build ----
__global__ void __launch_bounds__(256) k_hist(
        const int* __restrict__ dst, int* __restrict__ deg,
        int* __restrict__ rank) {
    int e = blockIdx.x * 256 + threadIdx.x;
    if (e >= N_EDGES) return;
    rank[e] = atomicAdd(&deg[dst[e]], 1);
}

__global__ void __launch_bounds__(256) k_scan1(
        const int* __restrict__ deg, int* __restrict__ bsum) {
    __shared__ int red[256];
    int t = threadIdx.x;
    int g = blockIdx.x * 256 + t;
    red[t] = (g < N_NODES) ? deg[g] : 0;
    __syncthreads();
    for (int s = 128; s > 0; s >>= 1) {
        if (t < s) red[t] += red[t + s];
        __syncthreads();
    }
    if (t == 0) bsum[blockIdx.x] = red[0];
}

__global__ void __launch_bounds__(512) k_scan2(
        const int* __restrict__ bsum, int* __restrict__ bpre) {
    __shared__ int sh[512];
    int t = threadIdx.x;
    int v = (t < SCAN_NBLK) ? bsum[t] : 0;
    sh[t] = v;
    __syncthreads();
    for (int d = 1; d < 512; d <<= 1) {
        int u = (t >= d) ? sh[t - d] : 0;
        __syncthreads();
        sh[t] += u;
        __syncthreads();
    }
    if (t < SCAN_NBLK) bpre[t] = sh[t] - v;   // exclusive
}

__global__ void __launch_bounds__(256) k_scan3(
        const int* __restrict__ deg, const int* __restrict__ bpre,
        int* __restrict__ off) {
    __shared__ int sh[256];
    int t = threadIdx.x;
    int g = blockIdx.x * 256 + t;
    int v = (g < N_NODES) ? deg[g] : 0;
    sh[t] = v;
    __syncthreads();
    for (int d = 1; d < 256; d <<= 1) {
        int u = (t >= d) ? sh[t - d] : 0;
        __syncthreads();
        sh[t] += u;
        __syncthreads();
    }
    int incl = sh[t];
    int base = bpre[blockIdx.x];
    if (g < N_NODES) off[g] = base + incl - v;
    if (g == N_NODES - 1) off[N_NODES] = base + incl;
}

// Scatter edge attrs (verbatim) + separate srcs[] array.
__global__ void __launch_bounds__(256) k_scatter(
        const int* __restrict__ src, const int* __restrict__ dst,
        const int* __restrict__ rank, const int* __restrict__ off,
        const float* __restrict__ eattr,
        unsigned int* __restrict__ rec, int* __restrict__ srcs) {
    int e = blockIdx.x * 256 + threadIdx.x;
    if (e >= N_EDGES) return;
    const uint4* ap = reinterpret_cast<const uint4*>(eattr + (size_t)e * F_EDGE);
    uint4 a0 = ap[0], a1 = ap[1];           // coalesced 32B read
    int pos = off[dst[e]] + rank[e];
    uint4* op = reinterpret_cast<uint4*>(rec + (size_t)pos * 8);
    op[0] = a0;                              // one 32B sector
    op[1] = a1;
    srcs[pos] = src[e];
}

// Pre-transpose GENConv MLP weights to bf16 once (verified in r7, absmax 0):
// W1t[l][j*64+k] = bf16(W1[l][k*128+j])   (j<128, k<64)
// W2t[l][c*128+j] = bf16(W2[l][j*64+c])   (c<64, j<128)
__global__ void __launch_bounds__(256) k_prep(
        const float* __restrict__ W1a, const float* __restrict__ W2a,
        const float* __restrict__ W1b, const float* __restrict__ W2b,
        const float* __restrict__ W1c, const float* __restrict__ W2c,
        u16* __restrict__ W1t, u16* __restrict__ W2t) {
    int bid = blockIdx.x;           // 192 blocks: 64 per layer
    int l = bid >> 6;
    int t = (bid & 63) * 256 + threadIdx.x;   // [0, 16384)
    const float* W1 = (l == 0) ? W1a : (l == 1) ? W1b : W1c;
    const float* W2 = (l == 0) ? W2a : (l == 1) ? W2b : W2c;
    if (t < HD * HD2) {             // W1t entry
        int j = t >> 6, k = t & 63;
        W1t[(size_t)l * HD * HD2 + t] = f2bf(W1[k * HD2 + j]);
    } else {
        int u = t - HD * HD2;
        int c = u >> 7, j = u & 127;
        W2t[(size_t)l * HD * HD2 + u] = f2bf(W2[j * HD + c]);
    }
}

// ---- GENConv aggregation (round-5 structure widened to 16-edge chunks) ----
// One wave per destination node (lane = feature), grid-stride persistent.
// Per 16-edge chunk: two per-lane coalesced 256B rec loads -> LDS broadcast;
// one 16-wide uniform srcs s_load; all 16 hb gathers batch-issued before
// compute. Mean degree = 16 -> most nodes finish in ONE gather epoch.
// One-chunk-ahead software pipeline as before. VGPR kept < 64 (r4 lesson).
__global__ void __launch_bounds__(256) k_gen_agg(
        const float* __restrict__ h, const u16* __restrict__ hb,
        const int* __restrict__ off,
        const unsigned int* __restrict__ rec,
        const int* __restrict__ srcs,
        const float* __restrict__ eW, const float* __restrict__ eb,
        float* __restrict__ outb) {
    __shared__ float sAttr[4][128];         // per-wave chunk staging, 2KB
    int wid = threadIdx.x >> 6;
    int lane = threadIdx.x & 63;
    int f = lane;
    float w[F_EDGE];
#pragma unroll
    for (int k = 0; k < F_EDGE; k++) w[k] = eW[k * HD + f];
    float bfv = eb[f];
    int wave0 = blockIdx.x * 4 + wid;
    const int NW = gridDim.x * 4;
    for (int n0 = wave0; n0 < N_NODES; n0 += NW) {
        int n = __builtin_amdgcn_readfirstlane(n0);
        int beg = off[n], end = off[n + 1];
        size_t idx = (size_t)n * HD + f;
        float hroot = h[idx];                 // hoisted; overlaps edge loop
        float den = 0.f, nm = 0.f;
        if (beg < end) {
            int i = beg;
            // prologue: chunk-0 rec (per-lane, guarded) + srcs (uniform s_load;
            // srcs has +64 zeroed pad so overrun reads are safe)
            float av0 = 0.f, av1 = 0.f;
            if (beg + (lane >> 3) < end) av0 = u2f(rec[(size_t)beg * 8 + lane]);
            if (beg + 8 + (lane >> 3) < end)
                av1 = u2f(rec[(size_t)(beg + 8) * 8 + lane]);
            int s16[16];
#pragma unroll
            for (int u = 0; u < 16; u++) s16[u] = srcs[beg + u];
            while (true) {
                // batch-issue all 16 gathers (pad/overrun srcs are valid node
                // ids or 0 -> safe reads; masked out in compute)
                float hv[16];
#pragma unroll
                for (int u = 0; u < 16; u++)
                    hv[u] = bf2f(hb[(size_t)s16[u] * HD + f]);
                // prefetch next chunk while gathers are in flight
                int inx = i + 16;
                bool more = inx < end;
                float av0N = 0.f, av1N = 0.f;
                int s16N[16];
                if (more) {
                    if (inx + (lane >> 3) < end)
                        av0N = u2f(rec[(size_t)inx * 8 + lane]);
                    if (inx + 8 + (lane >> 3) < end)
                        av1N = u2f(rec[(size_t)(inx + 8) * 8 + lane]);
#pragma unroll
                    for (int u = 0; u < 16; u++) s16N[u] = srcs[inx + u];
                } else {
#pragma unroll
                    for (int u = 0; u < 16; u++) s16N[u] = 0;
                }
                // stage current chunk's attrs to LDS (same wave: no barrier)
                sAttr[wid][lane] = av0;
                sAttr[wid][64 + lane] = av1;
#pragma unroll
                for (int u = 0; u < 16; u++) {
                    if (i + u < end) {       // uniform guard
                        const floatx4* A = reinterpret_cast<const floatx4*>(
                            &sAttr[wid][u * 8]);
                        floatx4 a0 = A[0], a1 = A[1];   // broadcast ds_read_b128
                        float ea = bfv + a0.x * w[0] + a0.y * w[1]
                                       + a0.z * w[2] + a0.w * w[3]
                                       + a1.x * w[4] + a1.y * w[5]
                                       + a1.z * w[6] + a1.w * w[7];
                        float r = fmaxf(hv[u] + ea, 0.f);
                        float ev = __expf(r);
                        den += ev;
                        nm += r * ev;
                    }
                }
                if (!more) break;
                i = inx;
                av0 = av0N;
                av1 = av1N;
#pragma unroll
                for (int u = 0; u < 16; u++) s16[u] = s16N[u];
            }
        }
        float agg = (end > beg) ? (nm / fmaxf(den, 1e-16f) + GEN_EPS) : 0.f;
        outb[idx] = hroot + agg;
    }
}

// ---- MLP (MFMA), v2: weights from pre-transposed bf16 global (L2-resident).
// LDS = sHid only (17.4KB -> 3 blocks/CU at the 64KB occupancy domain,
// vs 53.9KB -> 1 block/CU in the old version). hid rows are wave-private
// (same pattern verified in r7's k_layer) -> NO __syncthreads.
__global__ void __launch_bounds__(256) k_mlp(
        const float* __restrict__ inb,
        const u16* __restrict__ W1t, const float* __restrict__ b1,
        const u16* __restrict__ W2t, const float* __restrict__ b2,
        float* __restrict__ hout, u16* __restrict__ hbout) {
    __shared__ u16 sHid[64][HD2 + 8];   // [local n][j], 17.4 KB
    int tid = threadIdx.x;
    int wid = tid >> 6, lane = tid & 63;
    int quad = lane >> 4, lm = lane & 15;
    int n0 = blockIdx.x * 64 + wid * 16;
    if (n0 >= N_NODES) return;            // 100000 % 16 == 0: whole-tile guard
    int node = n0 + lm;
    short8 a[2];
    const float* ar = inb + (size_t)node * HD;
#pragma unroll
    for (int kk = 0; kk < 2; kk++) {
        const float4* p = reinterpret_cast<const float4*>(ar + kk * 32 + quad * 8);
        float4 v0 = p[0], v1 = p[1];
        short8 t;
        t[0] = (short)f2bf(v0.x); t[1] = (short)f2bf(v0.y);
        t[2] = (short)f2bf(v0.z); t[3] = (short)f2bf(v0.w);
        t[4] = (short)f2bf(v1.x); t[5] = (short)f2bf(v1.y);
        t[6] = (short)f2bf(v1.z); t[7] = (short)f2bf(v1.w);
        a[kk] = t;
    }
    // hid = relu(A @ W1 + b1): B-frags direct from global
#pragma unroll
    for (int jt = 0; jt < 8; jt++) {
        int jb = jt * 16;
        float bias = b1[jb + lm];
        floatx4 acc = {bias, bias, bias, bias};
#pragma unroll
        for (int kk = 0; kk < 2; kk++) {
            const short8* bp = reinterpret_cast<const short8*>(
                W1t + (size_t)(jb + lm) * HD + kk * 32 + quad * 8);
            acc = __builtin_amdgcn_mfma_f32_16x16x32_bf16(a[kk], *bp, acc, 0, 0, 0);
        }
#pragma unroll
        for (int r = 0; r < 4; r++) {
            int lr = wid * 16 + quad * 4 + r;
            sHid[lr][jb + lm] = f2bf(fmaxf(acc[r], 0.f));
        }
    }
    // out = relu(hid @ W2 + b2); hid rows wave-private -> no barrier
    short8 a2[4];
#pragma unroll
    for (int kk = 0; kk < 4; kk++)
        a2[kk] = *reinterpret_cast<const short8*>(
            &sHid[wid * 16 + lm][kk * 32 + quad * 8]);
#pragma unroll
    for (int ct = 0; ct < 4; ct++) {
        int cb = ct * 16;
        float bias = b2[cb + lm];
        floatx4 acc = {bias, bias, bias, bias};
#pragma unroll
        for (int kk = 0; kk < 4; kk++) {
            const short8* bp = reinterpret_cast<const short8*>(
                W2t + (size_t)(cb + lm) * HD2 + kk * 32 + quad * 8);
            acc = __builtin_amdgcn_mfma_f32_16x16x32_bf16(a2[kk], *bp, acc, 0, 0, 0);
        }
#pragma unroll
        for (int r = 0; r < 4; r++) {
            int orow = n0 + quad * 4 + r;
            float o = fmaxf(acc[r], 0.f);
            hout[(size_t)orow * HD + cb + lm] = o;
            hbout[(size_t)orow * HD + cb + lm] = f2bf(o);
        }
    }
}

// One wave per graph; range via inline binary search on sorted batch.
__global__ void __launch_bounds__(256) k_pool(
        const float* __restrict__ h, const int* __restrict__ batch,
        float* __restrict__ pooled) {
    int g = blockIdx.x * 4 + (threadIdx.x >> 6);
    if (g >= N_GRAPHS) return;
    int f = threadIdx.x & 63;
    int lo = 0, hi = N_NODES;
    while (lo < hi) {
        int mid = (lo + hi) >> 1;
        if (batch[mid] < g) lo = mid + 1; else hi = mid;
    }
    int b = lo;
    int lo2 = b, hi2 = N_NODES;
    while (lo2 < hi2) {
        int mid = (lo2 + hi2) >> 1;
        if (batch[mid] < g + 1) lo2 = mid + 1; else hi2 = mid;
    }
    int e = lo2;
    float s = 0.f;
    for (int n = b; n < e; n++) s += h[(size_t)n * HD + f];
    float cnt = fmaxf((float)(e - b), 1.f);
    pooled[(size_t)g * HD + f] = s / cnt;
}

__global__ void __launch_bounds__(64) k_head(
        const float* __restrict__ pooled, const float* __restrict__ gattr,
        const float* __restrict__ d1W, const float* __restrict__ d1b,
        const float* __restrict__ d2W, const float* __restrict__ d2b,
        const float* __restrict__ oW, const float* __restrict__ ob,
        float* __restrict__ out) {
    int g = blockIdx.x;
    __shared__ float si[HD + F_GRAPH];
    __shared__ float s1[32], s2[32];
    int t = threadIdx.x;
    if (t < HD) si[t] = pooled[(size_t)g * HD + t];
    if (t < F_GRAPH) si[HD + t] = gattr[(size_t)g * F_GRAPH + t];
    __syncthreads();
    if (t < 32) {
        float acc = d1b[t];
        for (int i = 0; i < HD + F_GRAPH; i++) acc += si[i] * d1W[i * 32 + t];
        s1[t] = fmaxf(acc, 0.f);
    }
    __syncthreads();
    if (t < 32) {
        float acc = d2b[t];
        for (int i = 0; i < 32; i++) acc += s1[i] * d2W[i * 32 + t];
        s2[t] = fmaxf(acc, 0.f);
    }
    __syncthreads();
    if (t == 0) {
        float acc = ob[0];
        for (int i = 0; i < 32; i++) acc += s2[i] * oW[i];
        out[g] = 1.f / (1.f + __expf(-acc));
    }
}

extern "C" void kernel_launch(void* const* d_in, const int* in_sizes, int n_in,
                              void* d_out, int out_size, void* d_ws, size_t ws_size,
                              hipStream_t stream) {
    const float* x     = (const float*)d_in[0];
    const float* eattr = (const float*)d_in[1];
    const float* gattr = (const float*)d_in[2];
    const int*   eidx  = (const int*)d_in[3];
    const int*   batch = (const int*)d_in[4];
    const float* nodeW = (const float*)d_in[5];
    const float* nodeb = (const float*)d_in[6];
    const float* edgeW = (const float*)d_in[7];
    const float* edgeb = (const float*)d_in[8];
    const float* cW1[3] = {(const float*)d_in[9],  (const float*)d_in[13], (const float*)d_in[17]};
    const float* cb1[3] = {(const float*)d_in[10], (const float*)d_in[14], (const float*)d_in[18]};
    const float* cW2[3] = {(const float*)d_in[11], (const float*)d_in[15], (const float*)d_in[19]};
    const float* cb2[3] = {(const float*)d_in[12], (const float*)d_in[16], (const float*)d_in[20]};
    const float* d1W = (const float*)d_in[21];
    const float* d1b = (const float*)d_in[22];
    const float* d2W = (const float*)d_in[23];
    const float* d2b = (const float*)d_in[24];
    const float* oW  = (const float*)d_in[25];
    const float* ob  = (const float*)d_in[26];

    const int* src = eidx;
    const int* dst = eidx + N_EDGES;

    // workspace layout (srcs padded +64 ints (zeroed), rec padded +8 records)
    char* p = (char*)d_ws;
    float* h      = (float*)p; p += (size_t)N_NODES * HD * 4;       // 25.6 MB
    float* outb   = (float*)p; p += (size_t)N_NODES * HD * 4;       // 25.6 MB
    int*   srcs   = (int*)p;   p += (size_t)(N_EDGES + 64) * 4;     // 6.4 MB + pad
    unsigned int* rec = (unsigned int*)p; p += (size_t)(N_EDGES + 8) * F_EDGE * 4; // 51.2 MB + pad
    u16*   hb     = (u16*)p;   p += (size_t)N_NODES * HD * 2;       // 12.8 MB
    u16*   W1t    = (u16*)p;   p += (size_t)3 * HD * HD2 * 2;       // 48 KB
    u16*   W2t    = (u16*)p;   p += (size_t)3 * HD * HD2 * 2;       // 48 KB
    float* pooled = (float*)p; p += (size_t)N_GRAPHS * HD * 4;
    int*   off    = (int*)p;   p += (size_t)(N_NODES + 1) * 4;
    int*   deg    = (int*)p;   p += (size_t)N_NODES * 4;
    int*   rank   = (int*)p;   p += (size_t)N_EDGES * 4;            // 6.4 MB
    int*   bsum   = (int*)p;   p += (size_t)(SCAN_NBLK + 1) * 4;
    int*   bpre   = (int*)p;   p += (size_t)(SCAN_NBLK + 1) * 4;

    const int EB = (N_EDGES + 255) / 256;
    const int NBM = (N_NODES + 63) / 64;   // 1563 MFMA blocks (64 nodes each)

    k_node_embed<<<(N_NODES * HD + 255) / 256, 256, 0, stream>>>(x, nodeW, nodeb, h, hb);
    k_prep<<<192, 256, 0, stream>>>(cW1[0], cW2[0], cW1[1], cW2[1], cW1[2], cW2[2],
                                    W1t, W2t);

    // CSR build (atomic-free scatter via hist-captured ranks)
    hipMemsetAsync(deg, 0, (size_t)N_NODES * 4, stream);
    hipMemsetAsync(srcs + N_EDGES, 0, 64 * sizeof(int), stream);   // valid pad
    k_hist<<<EB, 256, 0, stream>>>(dst, deg, rank);
    k_scan1<<<SCAN_NBLK, 256, 0, stream>>>(deg, bsum);
    k_scan2<<<1, 512, 0, stream>>>(bsum, bpre);
    k_scan3<<<SCAN_NBLK, 256, 0, stream>>>(deg, bpre, off);
    k_scatter<<<EB, 256, 0, stream>>>(src, dst, rank, off, eattr, rec, srcs);

    for (int l = 0; l < 3; l++) {
        k_gen_agg<<<2048, 256, 0, stream>>>(
            h, hb, off, rec, srcs, edgeW, edgeb, outb);
        k_mlp<<<NBM, 256, 0, stream>>>(outb,
                                       W1t + (size_t)l * HD * HD2, cb1[l],
                                       W2t + (size_t)l * HD * HD2, cb2[l],
                                       h, hb);
    }

    k_pool<<<(N_GRAPHS + 3) / 4, 256, 0, stream>>>(h, batch, pooled);
    k_head<<<N_GRAPHS, 64, 0, stream>>>(pooled, gattr,
                                        d1W, d1b, d2W, d2b, oW, ob,
                                        (float*)d_out);
}